// Round 5
// baseline (127.757 us; speedup 1.0000x reference)
//
#include <hip/hip_runtime.h>
#include <hip/hip_bf16.h>

#define WINDOW   2048
#define STRIDE   512
#define FREQ     1024
#define FRAMES   63
#define SIG_LEN  32256
#define BATCH    64
#define PAD      768
#define XPAD_LEN 33792            // SIG_LEN + 2*PAD
#define M_TOTAL  4032             // BATCH*FRAMES
#define N_TOTAL  2048             // 2*FREQ (real || imag)
#define K_TOTAL  2048             // WINDOW

#define BM 128
#define BN 128
#define BK 32

typedef __attribute__((ext_vector_type(8))) short short8;   // 8 bf16
typedef __attribute__((ext_vector_type(4))) float floatx4;  // 4 fp32 acc

__device__ __forceinline__ ushort f2bf(float f) {
    __hip_bfloat16 h = __float2bfloat16(f);
    return *reinterpret_cast<ushort*>(&h);
}

// ---------------------------------------------------------------------------
// Prep 1: zero-padded signal (fp32 -> bf16):
// xpad[b][i] = (768 <= i < 33024) ? bf16(x[b][i-768]) : 0
// ---------------------------------------------------------------------------
__global__ void pad_signal(const float4* __restrict__ x, uint4* __restrict__ xpad) {
    int id = blockIdx.x * blockDim.x + threadIdx.x;   // one per 8 bf16 out
    const int GP = XPAD_LEN / 8;                       // 4224 groups/batch
    if (id >= BATCH * GP) return;
    int b = id / GP, i = id - b * GP;
    ushort o[8] = {0, 0, 0, 0, 0, 0, 0, 0};
    int s = i - PAD / 8;                               // PAD divisible by 8
    if (s >= 0 && s < SIG_LEN / 8) {
        const float4* px = x + (size_t)b * (SIG_LEN / 4) + s * 2;
        float4 v0 = px[0], v1 = px[1];
        o[0] = f2bf(v0.x); o[1] = f2bf(v0.y); o[2] = f2bf(v0.z); o[3] = f2bf(v0.w);
        o[4] = f2bf(v1.x); o[5] = f2bf(v1.y); o[6] = f2bf(v1.z); o[7] = f2bf(v1.w);
    }
    xpad[id] = *(uint4*)o;
}

// ---------------------------------------------------------------------------
// Prep 2: Bt[n][k] = bf16((n<1024 ? Kr : Ki)[k][n mod 1024])  (B transposed),
// LDS-tiled 64x64 so both global read and write are fully coalesced.
// ---------------------------------------------------------------------------
__global__ void build_bt(const float* __restrict__ kr,
                         const float* __restrict__ ki,
                         ushort* __restrict__ bt) {
    __shared__ __align__(16) ushort tile[64][72];      // [k][n], +8 pad
    const int tid = threadIdx.x;                       // 256
    const int kt = blockIdx.x, nt = blockIdx.y;        // 32 x 32 tiles
    const int gn0 = nt * 64;
    const float* src = (gn0 < FREQ) ? kr : ki;
    const int n0 = gn0 - ((gn0 < FREQ) ? 0 : FREQ);
#pragma unroll
    for (int i = 0; i < 2; ++i) {                      // load rows of K (coalesced in n)
        int chunk = i * 256 + tid;
        int k = chunk >> 3, nc = chunk & 7;
        const float* p = src + (size_t)(kt * 64 + k) * FREQ + n0 + nc * 8;
        float4 v0 = *(const float4*)p;
        float4 v1 = *(const float4*)(p + 4);
        ushort tmp[8];
        tmp[0] = f2bf(v0.x); tmp[1] = f2bf(v0.y); tmp[2] = f2bf(v0.z); tmp[3] = f2bf(v0.w);
        tmp[4] = f2bf(v1.x); tmp[5] = f2bf(v1.y); tmp[6] = f2bf(v1.z); tmp[7] = f2bf(v1.w);
        *(uint4*)(&tile[k][nc * 8]) = *(uint4*)tmp;
    }
    __syncthreads();
#pragma unroll
    for (int i = 0; i < 2; ++i) {                      // store rows of Bt (coalesced in k)
        int chunk = i * 256 + tid;
        int n = chunk >> 3, kc = chunk & 7;
        ushort tmp[8];
#pragma unroll
        for (int j = 0; j < 8; ++j) tmp[j] = tile[kc * 8 + j][n];
        *(uint4*)(bt + (size_t)(gn0 + n) * K_TOTAL + kt * 64 + kc * 8) = *(uint4*)tmp;
    }
}

// ---------------------------------------------------------------------------
// GEMM: C[M=4032, N=2048] = A[M,K=2048] * B[K,N], bf16 in, fp32 acc,
// *** FP32 OUT *** (reference output dtype is float32 — R5 fix).
// 128x128 tile / 256 threads / 4 waves (each 64x64 via 4x4 of 16x16x32 MFMA).
// A and Bt staged with global_load_lds dwordx4 (wave-uniform LDS base).
// ---------------------------------------------------------------------------
__device__ __forceinline__ void gload16(const ushort* g, ushort* l) {
    __builtin_amdgcn_global_load_lds(
        (const __attribute__((address_space(1))) unsigned int*)g,
        (__attribute__((address_space(3))) unsigned int*)l,
        16, 0, 0);
}

__global__ __launch_bounds__(256) void stft_gemm(
    const ushort* __restrict__ xpad, const ushort* __restrict__ bt,
    float* __restrict__ out) {
    __shared__ __align__(16) ushort As[BM * BK];       // 8 KB, [m][k] row-major
    __shared__ __align__(16) ushort Bs[BN * BK];       // 8 KB, [n][k] row-major

    const int tid  = threadIdx.x;
    const int lane = tid & 63;
    const int w    = tid >> 6;                         // wave 0..3
    const int mtile = blockIdx.x;                      // 0..31
    const int ntile = blockIdx.y;                      // 0..15

    // --- staging assignment: wave w stages rows [w*16, w*16+16) and +64 ---
    const int srow = w * 16 + (lane >> 2);             // 0..63
    const int kcol = (lane & 3) * 8;                   // k offset in elems

    int gr0 = mtile * BM + srow;
    int gr1 = gr0 + 64;
    gr0 = min(gr0, M_TOTAL - 1);                       // clamp M-tail (stores masked)
    gr1 = min(gr1, M_TOTAL - 1);
    const int b0 = gr0 / FRAMES, t0 = gr0 - b0 * FRAMES;
    const int b1 = gr1 / FRAMES, t1 = gr1 - b1 * FRAMES;
    const ushort* gA0 = xpad + (size_t)b0 * XPAD_LEN + t0 * STRIDE + kcol;
    const ushort* gA1 = xpad + (size_t)b1 * XPAD_LEN + t1 * STRIDE + kcol;
    const ushort* gB0 = bt + (size_t)(ntile * BN + srow) * K_TOTAL + kcol;
    const ushort* gB1 = gB0 + (size_t)64 * K_TOTAL;

    ushort* ldsA0 = As + w * 512;                      // wave-uniform bases
    ushort* ldsA1 = As + 2048 + w * 512;
    ushort* ldsB0 = Bs + w * 512;
    ushort* ldsB1 = Bs + 2048 + w * 512;

    // --- fragment addressing ---
    const int wm = w >> 1, wn = w & 1;                 // wave -> 64x64 quadrant
    const int frow = lane & 15, fq = lane >> 4;
    const ushort* pA = As + (wm * 64 + frow) * BK + fq * 8;
    const ushort* pB = Bs + (wn * 64 + frow) * BK + fq * 8;

    floatx4 acc[4][4];
#pragma unroll
    for (int mi = 0; mi < 4; ++mi)
#pragma unroll
        for (int ni = 0; ni < 4; ++ni)
            acc[mi][ni] = (floatx4){0.f, 0.f, 0.f, 0.f};

    for (int kt = 0; kt < K_TOTAL / BK; ++kt) {
        __syncthreads();                               // LDS safe to overwrite
        gload16(gA0, ldsA0);
        gload16(gA1, ldsA1);
        gload16(gB0, ldsB0);
        gload16(gB1, ldsB1);
        gA0 += BK; gA1 += BK; gB0 += BK; gB1 += BK;
        __syncthreads();                               // staging complete

        short8 a[4], b[4];
#pragma unroll
        for (int mi = 0; mi < 4; ++mi) a[mi] = *(const short8*)(pA + mi * 16 * BK);
#pragma unroll
        for (int ni = 0; ni < 4; ++ni) b[ni] = *(const short8*)(pB + ni * 16 * BK);
#pragma unroll
        for (int mi = 0; mi < 4; ++mi)
#pragma unroll
            for (int ni = 0; ni < 4; ++ni)
                acc[mi][ni] = __builtin_amdgcn_mfma_f32_16x16x32_bf16(
                    a[mi], b[ni], acc[mi][ni], 0, 0, 0);
    }

    // --- epilogue: C/D layout col=lane&15, row=(lane>>4)*4+reg; fp32 stores ---
    const int orow0 = mtile * BM + wm * 64 + fq * 4;
    const bool is_imag = (ntile >= 8);
    float* outp = out + (is_imag ? (size_t)M_TOTAL * FREQ : 0);
    const int ncol0 = (ntile - (is_imag ? 8 : 0)) * BN + wn * 64 + frow;

#pragma unroll
    for (int mi = 0; mi < 4; ++mi) {
#pragma unroll
        for (int r = 0; r < 4; ++r) {
            int grow = orow0 + mi * 16 + r;
            if (grow < M_TOTAL) {
                float* orow = outp + (size_t)grow * FREQ + ncol0;
#pragma unroll
                for (int ni = 0; ni < 4; ++ni)
                    orow[ni * 16] = acc[mi][ni][r];
            }
        }
    }
}

extern "C" void kernel_launch(void* const* d_in, const int* in_sizes, int n_in,
                              void* d_out, int out_size, void* d_ws, size_t ws_size,
                              hipStream_t stream) {
    const float* x  = (const float*)d_in[0];   // fp32 [64, 32256, 1]
    const float* kr = (const float*)d_in[1];   // fp32 [2048, 1, 1024]
    const float* ki = (const float*)d_in[2];   // fp32 [2048, 1, 1024]

    ushort* xpad = (ushort*)d_ws;                               // 64*33792 bf16 (4.3 MB)
    ushort* btm  = xpad + (size_t)BATCH * XPAD_LEN;             // 2048*2048 bf16 (8 MB)

    pad_signal<<<(BATCH * XPAD_LEN / 8 + 255) / 256, 256, 0, stream>>>(
        (const float4*)x, (uint4*)xpad);
    build_bt<<<dim3(K_TOTAL / 64, N_TOTAL / 64), 256, 0, stream>>>(kr, ki, btm);
    stft_gemm<<<dim3((M_TOTAL + BM - 1) / BM, N_TOTAL / BN), 256, 0, stream>>>(
        xpad, btm, (float*)d_out);
}

// Round 7
// 118.611 us; speedup vs baseline: 1.0771x; 1.0771x over previous
//
#include <hip/hip_runtime.h>
#include <hip/hip_bf16.h>

#define WINDOW   2048
#define STRIDE   512
#define FREQ     1024
#define FRAMES   63
#define SIG_LEN  32256
#define BATCH    64
#define PAD      768
#define XPAD_LEN 33792            // SIG_LEN + 2*PAD
#define M_TOTAL  4032             // BATCH*FRAMES
#define N_TOTAL  2048             // 2*FREQ (real || imag)
#define K_TOTAL  2048             // WINDOW

#define BM 128
#define BN 128
#define BK 64                     // two 32-wide half-buffers

typedef __attribute__((ext_vector_type(8))) short short8;   // 8 bf16
typedef __attribute__((ext_vector_type(4))) float floatx4;  // 4 fp32 acc

__device__ __forceinline__ ushort f2bf(float f) {
    __hip_bfloat16 h = __float2bfloat16(f);
    return *reinterpret_cast<ushort*>(&h);
}

// ---------------------------------------------------------------------------
// Prep 1: zero-padded signal (fp32 -> bf16)
// ---------------------------------------------------------------------------
__global__ void pad_signal(const float4* __restrict__ x, uint4* __restrict__ xpad) {
    int id = blockIdx.x * blockDim.x + threadIdx.x;   // one per 8 bf16 out
    const int GP = XPAD_LEN / 8;                       // 4224 groups/batch
    if (id >= BATCH * GP) return;
    int b = id / GP, i = id - b * GP;
    ushort o[8] = {0, 0, 0, 0, 0, 0, 0, 0};
    int s = i - PAD / 8;
    if (s >= 0 && s < SIG_LEN / 8) {
        const float4* px = x + (size_t)b * (SIG_LEN / 4) + s * 2;
        float4 v0 = px[0], v1 = px[1];
        o[0] = f2bf(v0.x); o[1] = f2bf(v0.y); o[2] = f2bf(v0.z); o[3] = f2bf(v0.w);
        o[4] = f2bf(v1.x); o[5] = f2bf(v1.y); o[6] = f2bf(v1.z); o[7] = f2bf(v1.w);
    }
    xpad[id] = *(uint4*)o;
}

// ---------------------------------------------------------------------------
// Prep 2: Bt[n][k] = bf16((n<1024 ? Kr : Ki)[k][n mod 1024])
// ---------------------------------------------------------------------------
__global__ void build_bt(const float* __restrict__ kr,
                         const float* __restrict__ ki,
                         ushort* __restrict__ bt) {
    __shared__ __align__(16) ushort tile[64][72];
    const int tid = threadIdx.x;                       // 256
    const int kt = blockIdx.x, nt = blockIdx.y;        // 32 x 32 tiles
    const int gn0 = nt * 64;
    const float* src = (gn0 < FREQ) ? kr : ki;
    const int n0 = gn0 - ((gn0 < FREQ) ? 0 : FREQ);
#pragma unroll
    for (int i = 0; i < 2; ++i) {
        int chunk = i * 256 + tid;
        int k = chunk >> 3, nc = chunk & 7;
        const float* p = src + (size_t)(kt * 64 + k) * FREQ + n0 + nc * 8;
        float4 v0 = *(const float4*)p;
        float4 v1 = *(const float4*)(p + 4);
        ushort tmp[8];
        tmp[0] = f2bf(v0.x); tmp[1] = f2bf(v0.y); tmp[2] = f2bf(v0.z); tmp[3] = f2bf(v0.w);
        tmp[4] = f2bf(v1.x); tmp[5] = f2bf(v1.y); tmp[6] = f2bf(v1.z); tmp[7] = f2bf(v1.w);
        *(uint4*)(&tile[k][nc * 8]) = *(uint4*)tmp;
    }
    __syncthreads();
#pragma unroll
    for (int i = 0; i < 2; ++i) {
        int chunk = i * 256 + tid;
        int n = chunk >> 3, kc = chunk & 7;
        ushort tmp[8];
#pragma unroll
        for (int j = 0; j < 8; ++j) tmp[j] = tile[kc * 8 + j][n];
        *(uint4*)(bt + (size_t)(gn0 + n) * K_TOTAL + kt * 64 + kc * 8) = *(uint4*)tmp;
    }
}

// ---------------------------------------------------------------------------
// GEMM: C[4032,2048] = A[4032,2048] * B[2048,2048], bf16 in, fp32 acc/out.
// R6/R7: (1) XOR bank-swizzle on 16B k-chunks (conflict-free b128 reads),
//        (2) BK=64 as two 32-wide half-buffers (half the barriers).
// LDS layout per half: [128 rows][32 elems] row-major; chunk c of row r is
// stored at position c ^ ((r>>1)&3). Staging lane fetches the global chunk
// belonging at its fixed LDS slot (wave-uniform base + lane*16B).
// ---------------------------------------------------------------------------
__device__ __forceinline__ void gload16(const ushort* g, ushort* l) {
    __builtin_amdgcn_global_load_lds(
        (const __attribute__((address_space(1))) unsigned int*)g,
        (__attribute__((address_space(3))) unsigned int*)l,
        16, 0, 0);
}

__global__ __launch_bounds__(256) void stft_gemm(
    const ushort* __restrict__ xpad, const ushort* __restrict__ bt,
    float* __restrict__ out) {
    __shared__ __align__(16) ushort As[2 * BM * 32];   // 16 KB: [kk][128][32]
    __shared__ __align__(16) ushort Bs[2 * BN * 32];   // 16 KB

    const int tid  = threadIdx.x;
    const int lane = tid & 63;
    const int w    = tid >> 6;                         // wave 0..3
    const int mtile = blockIdx.x;                      // 0..31
    const int ntile = blockIdx.y;                      // 0..15

    // --- staging: wave w stages rows [w*16, w*16+16) of each 64-row slice ---
    const int srow = w * 16 + (lane >> 2);             // 0..63
    // lane's LDS slot holds swizzled chunk pos c'=lane&3; fetch global chunk
    // c = c' ^ ((srow>>1)&3) = (lane&3) ^ ((lane>>3)&3)
    const int kcol = ((lane & 3) ^ ((lane >> 3) & 3)) * 8;

    int gr0 = mtile * BM + srow;
    int gr1 = gr0 + 64;
    gr0 = min(gr0, M_TOTAL - 1);                       // clamp M-tail (stores masked)
    gr1 = min(gr1, M_TOTAL - 1);
    const int b0 = gr0 / FRAMES, t0 = gr0 - b0 * FRAMES;
    const int b1 = gr1 / FRAMES, t1 = gr1 - b1 * FRAMES;
    const ushort* gA0 = xpad + (size_t)b0 * XPAD_LEN + t0 * STRIDE + kcol;
    const ushort* gA1 = xpad + (size_t)b1 * XPAD_LEN + t1 * STRIDE + kcol;
    const ushort* gB0 = bt + (size_t)(ntile * BN + srow) * K_TOTAL + kcol;
    const ushort* gB1 = gB0 + (size_t)64 * K_TOTAL;

    ushort* ldsA0 = As + w * 512;                      // wave-uniform bases
    ushort* ldsA1 = As + 2048 + w * 512;
    ushort* ldsB0 = Bs + w * 512;
    ushort* ldsB1 = Bs + 2048 + w * 512;

    // --- fragment addressing (swizzled chunk) ---
    const int wm = w >> 1, wn = w & 1;                 // wave -> 64x64 quadrant
    const int frow = lane & 15, fq = lane >> 4;
    const int cs = (fq ^ ((frow >> 1) & 3)) * 8;       // swizzled chunk offset
    const ushort* pA = As + (wm * 64 + frow) * 32 + cs;
    const ushort* pB = Bs + (wn * 64 + frow) * 32 + cs;

    floatx4 acc[4][4];
#pragma unroll
    for (int mi = 0; mi < 4; ++mi)
#pragma unroll
        for (int ni = 0; ni < 4; ++ni)
            acc[mi][ni] = (floatx4){0.f, 0.f, 0.f, 0.f};

    for (int kt = 0; kt < K_TOTAL / BK; ++kt) {        // 32 iters
        __syncthreads();                               // LDS safe to overwrite
        gload16(gA0,      ldsA0);
        gload16(gA0 + 32, ldsA0 + 4096);               // k-half 1
        gload16(gA1,      ldsA1);
        gload16(gA1 + 32, ldsA1 + 4096);
        gload16(gB0,      ldsB0);
        gload16(gB0 + 32, ldsB0 + 4096);
        gload16(gB1,      ldsB1);
        gload16(gB1 + 32, ldsB1 + 4096);
        gA0 += BK; gA1 += BK; gB0 += BK; gB1 += BK;
        __syncthreads();                               // staging complete

#pragma unroll
        for (int kk = 0; kk < 2; ++kk) {
            short8 a[4], b[4];
#pragma unroll
            for (int mi = 0; mi < 4; ++mi)
                a[mi] = *(const short8*)(pA + kk * 4096 + mi * 512);
#pragma unroll
            for (int ni = 0; ni < 4; ++ni)
                b[ni] = *(const short8*)(pB + kk * 4096 + ni * 512);
#pragma unroll
            for (int mi = 0; mi < 4; ++mi)
#pragma unroll
                for (int ni = 0; ni < 4; ++ni)
                    acc[mi][ni] = __builtin_amdgcn_mfma_f32_16x16x32_bf16(
                        a[mi], b[ni], acc[mi][ni], 0, 0, 0);
        }
    }

    // --- epilogue: C/D layout col=lane&15, row=(lane>>4)*4+reg; fp32 stores ---
    const int orow0 = mtile * BM + wm * 64 + fq * 4;
    const bool is_imag = (ntile >= 8);
    float* outp = out + (is_imag ? (size_t)M_TOTAL * FREQ : 0);
    const int ncol0 = (ntile - (is_imag ? 8 : 0)) * BN + wn * 64 + frow;

#pragma unroll
    for (int mi = 0; mi < 4; ++mi) {
#pragma unroll
        for (int r = 0; r < 4; ++r) {
            int grow = orow0 + mi * 16 + r;
            if (grow < M_TOTAL) {
                float* orow = outp + (size_t)grow * FREQ + ncol0;
#pragma unroll
                for (int ni = 0; ni < 4; ++ni)
                    orow[ni * 16] = acc[mi][ni][r];
            }
        }
    }
}

extern "C" void kernel_launch(void* const* d_in, const int* in_sizes, int n_in,
                              void* d_out, int out_size, void* d_ws, size_t ws_size,
                              hipStream_t stream) {
    const float* x  = (const float*)d_in[0];   // fp32 [64, 32256, 1]
    const float* kr = (const float*)d_in[1];   // fp32 [2048, 1, 1024]
    const float* ki = (const float*)d_in[2];   // fp32 [2048, 1, 1024]

    ushort* xpad = (ushort*)d_ws;                               // 4.3 MB
    ushort* btm  = xpad + (size_t)BATCH * XPAD_LEN;             // 8 MB

    pad_signal<<<(BATCH * XPAD_LEN / 8 + 255) / 256, 256, 0, stream>>>(
        (const float4*)x, (uint4*)xpad);
    build_bt<<<dim3(K_TOTAL / 64, N_TOTAL / 64), 256, 0, stream>>>(kr, ki, btm);
    stft_gemm<<<dim3((M_TOTAL + BM - 1) / BM, N_TOTAL / BN), 256, 0, stream>>>(
        xpad, btm, (float*)d_out);
}